// Round 14
// baseline (199.454 us; speedup 1.0000x reference)
//
#include <hip/hip_runtime.h>

#define N 8192
#define DIN 64
#define DOUT 128
#define KNN 16
#define MSAMP 2048         /* presample columns, stride 4 */
#define NBX 8              /* j-split in main scan */
#define CAND_R 64          /* slots per (row, bx) region */
#define CAND_C (NBX * CAND_R)   /* 512 per row */
#define EPS 1.0f           /* candidate-gate margin (passed r8-r13) */
#define DELTA_Q 64         /* verify-gate margin: 0.5 in dist units */
#define VCAP 128           /* verify-list capacity (expect ~45) */
#define PSTR 2052          /* prek LDS row stride in u16 (bank stagger) */
#define ROWS_PRE 16

typedef unsigned long long u64;
typedef __attribute__((ext_vector_type(8))) short bf16x8;
typedef __attribute__((ext_vector_type(4))) float floatx4;

__device__ __forceinline__ unsigned mono(float f) {
    unsigned u = __float_as_uint(f);
    return (u & 0x80000000u) ? ~u : (u | 0x80000000u);
}
__device__ __forceinline__ unsigned short f2bf(float f) {   // RNE float->bf16
    unsigned u = __float_as_uint(f);
    return (unsigned short)((u + 0x7FFFu + ((u >> 16) & 1u)) >> 16);
}
__device__ __forceinline__ unsigned qdist(float dist) {     // round-up quant
    int q = (int)(dist * 128.0f) + 2;
    q = max(q, 0); return (unsigned)min(q, 65535);
}

// K1: fused pre: sq, sqs, bf16 Xh, U = x@(W1a-W1b)+b1, V = x@W1b.
__global__ __launch_bounds__(256) void k_pre(const float* __restrict__ x,
                                             const float* __restrict__ W1,
                                             const float* __restrict__ b1,
                                             float* __restrict__ sq,
                                             float* __restrict__ sqs,
                                             unsigned short* __restrict__ Xh,
                                             float* __restrict__ U,
                                             float* __restrict__ V) {
    __shared__ float xs[ROWS_PRE][DIN];
    int t = threadIdx.x;
    int r0 = blockIdx.x * ROWS_PRE;
    float4 xv = ((const float4*)x)[(size_t)r0 * (DIN / 4) + t];
    ((float4*)xs)[t] = xv;
    ushort4 h4;
    h4.x = f2bf(xv.x); h4.y = f2bf(xv.y);
    h4.z = f2bf(xv.z); h4.w = f2bf(xv.w);
    *(ushort4*)&Xh[r0 * DIN + t * 4] = h4;
    __syncthreads();
    if (t < ROWS_PRE) {
        const float4* xr = (const float4*)xs[t];
        float s0 = 0.f, s1 = 0.f, s2 = 0.f, s3 = 0.f;
#pragma unroll
        for (int q = 0; q < DIN / 4; ++q) {
            float4 a = xr[q];
            s0 = fmaf(a.x, a.x, s0); s1 = fmaf(a.y, a.y, s1);
            s2 = fmaf(a.z, a.z, s2); s3 = fmaf(a.w, a.w, s3);
        }
        float sv = (s0 + s1) + (s2 + s3);
        sq[r0 + t] = sv;
        if ((t & 3) == 0) sqs[(r0 + t) >> 2] = sv;   // sampled rows j = 4*scol
    }
    int o = t & 127, g = t >> 7;
    float aU[8], aV[8];
#pragma unroll
    for (int u = 0; u < 8; ++u) { aU[u] = 0.f; aV[u] = 0.f; }
    for (int kk = 0; kk < DIN; ++kk) {
        float whi = W1[kk * DOUT + o];
        float wlo = W1[(DIN + kk) * DOUT + o];
        float wd = whi - wlo;
#pragma unroll
        for (int u = 0; u < 8; ++u) {
            float xvv = xs[g * 8 + u][kk];
            aU[u] = fmaf(xvv, wd, aU[u]);
            aV[u] = fmaf(xvv, wlo, aV[u]);
        }
    }
    float bb = b1[o];
#pragma unroll
    for (int u = 0; u < 8; ++u) {
        int r = r0 + g * 8 + u;
        U[(size_t)r * DOUT + o] = aU[u] + bb;
        V[(size_t)r * DOUT + o] = aV[u];
    }
}

// K2: fused presample + tau. One block = 16 i-rows. 32 stages x 64 staged
// sample rows (wave w computes its 16-sample MFMA group, k_main orientation:
// acc row = quad*4+reg, col = m). q16 -> LDS prek (no HBM round-trip), then
// each wave radix-selects the exact sampled 16th for 4 rows.
__global__ __launch_bounds__(256) void k_pretau(const unsigned short* __restrict__ Xh,
                                                const float* __restrict__ sq,
                                                const float* __restrict__ sqs,
                                                float* __restrict__ tauf) {
    __shared__ __align__(16) short ldsH[64 * 72];           //  9.0 KB
    __shared__ unsigned short prek[16][PSTR];               // 64.1 KB
    int tid = threadIdx.x, w = tid >> 6, l = tid & 63;
    int m = l & 15, ko = (l >> 4) * 8, quad = l >> 4;
    int rt = blockIdx.x;
    size_t arow = (size_t)(rt * 16 + m) * DIN;
    bf16x8 aH0 = *(const bf16x8*)(Xh + arow + ko);          // i-row frags (A)
    bf16x8 aH1 = *(const bf16x8*)(Xh + arow + 32 + ko);
    float si[4];
#pragma unroll
    for (int reg = 0; reg < 4; ++reg) si[reg] = sq[rt * 16 + quad * 4 + reg];
    int srw = tid >> 3, scol8 = (tid & 7) * 8;
    for (int st = 0; st < 32; ++st) {
        int sbase = st * 64;
        __syncthreads();
        *(bf16x8*)&ldsH[srw * 72 + scol8] =
            *(const bf16x8*)(Xh + (size_t)(4 * (sbase + srw)) * DIN + scol8);
        *(bf16x8*)&ldsH[(srw + 32) * 72 + scol8] =
            *(const bf16x8*)(Xh + (size_t)(4 * (sbase + srw + 32)) * DIN + scol8);
        __syncthreads();
        int br = w * 16 + m;                                // wave w -> group w
        bf16x8 bH0 = *(const bf16x8*)&ldsH[br * 72 + ko];
        bf16x8 bH1 = *(const bf16x8*)&ldsH[br * 72 + 32 + ko];
        floatx4 acc = {0.f, 0.f, 0.f, 0.f};
        acc = __builtin_amdgcn_mfma_f32_16x16x32_bf16(aH0, bH0, acc, 0, 0, 0);
        acc = __builtin_amdgcn_mfma_f32_16x16x32_bf16(aH1, bH1, acc, 0, 0, 0);
        int scol = sbase + w * 16 + m;
        float sqj = sqs[scol];
#pragma unroll
        for (int reg = 0; reg < 4; ++reg) {
            float dist = fmaf(-2.0f, acc[reg], si[reg] + sqj);
            prek[quad * 4 + reg][scol] = (unsigned short)qdist(dist);
        }
    }
    __syncthreads();
#pragma unroll
    for (int rr = 0; rr < 4; ++rr) {            // wave w owns rows w*4+rr
        int lr = w * 4 + rr;
        unsigned v[MSAMP / 64];
#pragma unroll
        for (int u = 0; u < MSAMP / 64; ++u)
            v[u] = prek[lr][l + 64 * u];        // consecutive u16 -> no conflict
        unsigned p = 0;                         // invariant: #{q < p} < 16
#pragma unroll
        for (int b = 15; b >= 0; --b) {
            unsigned c16 = p | (1u << b);
            int cnt = 0;
#pragma unroll
            for (int u = 0; u < MSAMP / 64; ++u)
                cnt += __popcll(__ballot(v[u] < c16));
            if (cnt < 16) p = c16;              // wave-uniform
        }
        if (l == 0) tauf[rt * 16 + lr] = (float)p * (1.0f / 128.0f);
    }
}

// K3: MFMA main scan (r12-verified). Passers append u32 (q<<16)|j via
// ballot-prefix slots into exclusive (row,bx) regions.
__global__ __launch_bounds__(256, 4) void k_main(const unsigned short* __restrict__ Xh,
                                                 const float* __restrict__ sq,
                                                 const float* __restrict__ tauf,
                                                 unsigned* __restrict__ cand,
                                                 unsigned* __restrict__ cntpart) {
    __shared__ __align__(16) short ldsH[64 * 72];
    int tid = threadIdx.x, w = tid >> 6, l = tid & 63;
    int m = l & 15, ko = (l >> 4) * 8;
    int bx = blockIdx.x;
    int rt = blockIdx.y * 4 + w;
    size_t arow = (size_t)(rt * 16 + m) * DIN;
    bf16x8 aH0 = *(const bf16x8*)(Xh + arow + ko);
    bf16x8 aH1 = *(const bf16x8*)(Xh + arow + 32 + ko);
    int rg[4]; float T[4]; float si[4]; int rowcnt[4];
#pragma unroll
    for (int reg = 0; reg < 4; ++reg) {
        rg[reg] = rt * 16 + (l >> 4) * 4 + reg;
        si[reg] = sq[rg[reg]];
        T[reg] = tauf[rg[reg]] + EPS - si[reg];
        rowcnt[reg] = 0;
    }
    int qs = l & 48;
    unsigned lmask = (1u << (l & 15)) - 1u;
    int srw = tid >> 3, scol8 = (tid & 7) * 8;

    for (int st = 0; st < 16; ++st) {
        int jbase = bx * 1024 + st * 64;
        __syncthreads();
        *(bf16x8*)&ldsH[srw * 72 + scol8] =
            *(const bf16x8*)(Xh + (size_t)(jbase + srw) * DIN + scol8);
        *(bf16x8*)&ldsH[(srw + 32) * 72 + scol8] =
            *(const bf16x8*)(Xh + (size_t)(jbase + srw + 32) * DIN + scol8);
        __syncthreads();
#pragma unroll
        for (int it = 0; it < 4; ++it) {
            int br = it * 16 + m;
            bf16x8 bH0 = *(const bf16x8*)&ldsH[br * 72 + ko];
            bf16x8 bH1 = *(const bf16x8*)&ldsH[br * 72 + 32 + ko];
            floatx4 acc = {0.f, 0.f, 0.f, 0.f};
            acc = __builtin_amdgcn_mfma_f32_16x16x32_bf16(aH0, bH0, acc, 0, 0, 0);
            acc = __builtin_amdgcn_mfma_f32_16x16x32_bf16(aH1, bH1, acc, 0, 0, 0);
            int jcol = jbase + it * 16 + m;
            float sqj = sq[jcol];
#pragma unroll
            for (int reg = 0; reg < 4; ++reg) {
                float tv = fmaf(-2.0f, acc[reg], sqj);   // dist - si
                bool pass = tv <= T[reg];
                u64 bal = __ballot(pass);
                if (bal) {                               // skip empty
                    unsigned m16 = (unsigned)((bal >> qs) & 0xFFFFull);
                    if (pass) {
                        int slot = rowcnt[reg] + __popc(m16 & lmask);
                        if (slot < CAND_R)
                            cand[(size_t)rg[reg] * CAND_C + bx * CAND_R + slot] =
                                (qdist(tv + si[reg]) << 16) | (unsigned)jcol;
                    }
                    rowcnt[reg] += __popc(m16);
                }
            }
        }
    }
    if ((l & 15) == 0) {
#pragma unroll
        for (int reg = 0; reg < 4; ++reg)
            cntpart[rg[reg] * NBX + bx] = (unsigned)min(rowcnt[reg], CAND_R);
    }
}

// K4: verify-gated exact top-16 (r12-verified). radix-select q16 -> verify
// {q <= q16+DELTA_Q} -> exact striped fp32 dot (order == r1-r13) ->
// LDS all-pairs rank-select. Output bit-identical.
__global__ __launch_bounds__(256) void k_exact(const float* __restrict__ x,
                                               const float* __restrict__ sq,
                                               const unsigned* __restrict__ cntpart,
                                               const unsigned* __restrict__ cand,
                                               int* __restrict__ knn) {
    __shared__ unsigned cj[4][CAND_C];          // 8 KB
    __shared__ unsigned short vlist[4][VCAP];   // 1 KB
    __shared__ u64 ekeys[4][VCAP];              // 4 KB
    int w = threadIdx.x >> 6, l = threadIdx.x & 63;
    int row = blockIdx.x * 4 + w;
    int base = 0;
#pragma unroll
    for (int b = 0; b < NBX; ++b) {             // compact candidate list
        int c = (int)cntpart[row * NBX + b];    // wave-uniform -> scalar
        c = min(c, CAND_R);
        if (l < c) cj[w][base + l] = cand[(size_t)row * CAND_C + b * CAND_R + l];
        base += c;
    }
    __syncthreads();
    unsigned kk[CAND_C / 64], qq[CAND_C / 64];
#pragma unroll
    for (int u = 0; u < CAND_C / 64; ++u) {
        int idx = l + 64 * u;
        kk[u] = (idx < base) ? cj[w][idx] : 0xFFFFFFFFu;
        qq[u] = (idx < base) ? (kk[u] >> 16) : 0xFFFFFFFFu;
    }
    unsigned p = 0;                             // radix-select q16
#pragma unroll
    for (int b = 15; b >= 0; --b) {
        unsigned c16 = p | (1u << b);
        int cnt = 0;
#pragma unroll
        for (int u = 0; u < CAND_C / 64; ++u)
            cnt += __popcll(__ballot(qq[u] < c16));
        if (cnt < 16) p = c16;
    }
    unsigned thr = p + DELTA_Q;                 // verify gate on q
    int nv = 0;
    u64 lm = (l == 63) ? 0xFFFFFFFFFFFFFFFFull >> 1 : (1ull << l) - 1ull;
#pragma unroll
    for (int u = 0; u < CAND_C / 64; ++u) {
        bool pred = qq[u] <= thr;               // invalid qq -> false
        u64 bal = __ballot(pred);
        int slot = nv + __popcll(bal & lm);
        if (pred && slot < VCAP) vlist[w][slot] = (unsigned short)(kk[u] & 0xFFFFu);
        nv += __popcll(bal);
    }
    nv = min(nv, VCAP);
    __syncthreads();
    float sqi = sq[row];
    const float* xi = x + (size_t)row * DIN;    // wave-uniform -> SGPRs
#pragma unroll
    for (int r = 0; r < VCAP / 64; ++r) {
        int v = l + 64 * r;
        if (v < nv) {
            int j = (int)vlist[w][v];
            const float4* bj = (const float4*)(x + (size_t)j * DIN);
            float4 rb[16];
#pragma unroll
            for (int q = 0; q < DIN / 4; ++q) rb[q] = bj[q];
            float s0 = 0.f, s1 = 0.f, s2 = 0.f, s3 = 0.f;
#pragma unroll
            for (int q = 0; q < DIN / 4; ++q) {  // striped order == r1-r13
                s0 = fmaf(xi[4 * q + 0], rb[q].x, s0);
                s1 = fmaf(xi[4 * q + 1], rb[q].y, s1);
                s2 = fmaf(xi[4 * q + 2], rb[q].z, s2);
                s3 = fmaf(xi[4 * q + 3], rb[q].w, s3);
            }
            float d = (s0 + s1) + (s2 + s3);
            float dist = fmaf(-2.0f, d, sqi + sq[j]);
            ekeys[w][v] = ((u64)mono(dist) << 32) | (unsigned)j;
        }
    }
#pragma unroll
    for (int r = 0; r < VCAP / 64; ++r) {       // all-pairs rank-select
        int v = l + 64 * r;
        if (v < nv) {
            u64 mykey = ekeys[w][v];
            int rank = 0;
            for (int i = 0; i < nv; ++i)
                rank += (ekeys[w][i] < mykey) ? 1 : 0;
            if (rank < KNN)
                knn[row * KNN + rank] = (int)(unsigned)(mykey & 0xFFFFFFFFull);
        }
    }
}

// K5: agg = mean relu(U_i + V_j); out = agg@W2 + b2 (r12-verified). 8 rows
// per block, W2 staged through LDS in 16 KB coalesced tiles.
__global__ __launch_bounds__(256) void k_aggout(const float* __restrict__ U,
                                                const float* __restrict__ V,
                                                const int* __restrict__ knn,
                                                const float* __restrict__ W2,
                                                const float* __restrict__ b2,
                                                float* __restrict__ out) {
    __shared__ float ag[8][DOUT];       // 4 KB
    __shared__ float w2t[32 * DOUT];    // 16 KB
    int t = threadIdx.x;
    int o = t & 127, g = t >> 7;        // g in {0,1}; rows g*4 + r
    int i0 = blockIdx.x * 8 + g * 4;
#pragma unroll
    for (int r = 0; r < 4; ++r) {
        int i = i0 + r;
        float u = U[(size_t)i * DOUT + o];
        const int* nb = knn + i * KNN;  // wave-uniform
        float acc = 0.f;
#pragma unroll
        for (int q = 0; q < KNN; ++q)
            acc += fmaxf(u + V[(size_t)nb[q] * DOUT + o], 0.0f);
        ag[g * 4 + r][o] = acc * (1.0f / KNN);
    }
    float a2[4] = {0.f, 0.f, 0.f, 0.f};
#pragma unroll
    for (int tile = 0; tile < 4; ++tile) {
        __syncthreads();
#pragma unroll
        for (int u = 0; u < 4; ++u)     // 16 KB coalesced stage
            ((float4*)w2t)[t + u * 256] =
                ((const float4*)(W2 + tile * 32 * DOUT))[t + u * 256];
        __syncthreads();
#pragma unroll 8
        for (int kk = 0; kk < 32; ++kk) {
            float wv = w2t[kk * DOUT + o];
#pragma unroll
            for (int r = 0; r < 4; ++r)
                a2[r] = fmaf(ag[g * 4 + r][tile * 32 + kk], wv, a2[r]);
        }
    }
    float bb = b2[o];
#pragma unroll
    for (int r = 0; r < 4; ++r)
        out[(size_t)(i0 + r) * DOUT + o] = a2[r] + bb;
}

extern "C" void kernel_launch(void* const* d_in, const int* in_sizes, int n_in,
                              void* d_out, int out_size, void* d_ws, size_t ws_size,
                              hipStream_t stream) {
    const float* x  = (const float*)d_in[0];
    const float* W1 = (const float*)d_in[1];
    const float* b1 = (const float*)d_in[2];
    const float* W2 = (const float*)d_in[3];
    const float* b2 = (const float*)d_in[4];
    float* out = (float*)d_out;

    char* ws = (char*)d_ws;
    float*          sq      = (float*)(ws);                      // 32 KB
    float*          sqs     = (float*)(ws + 32768);              // 8 KB
    float*          tauf    = (float*)(ws + 40960);              // 32 KB
    int*            knn     = (int*)(ws + 73728);                // 512 KB
    unsigned short* Xh      = (unsigned short*)(ws + 655360);    // 1 MB
    unsigned*       cntpart = (unsigned*)(ws + 1703936);         // 256 KB
    float*          U       = (float*)(ws + 2097152);            // 4 MB
    float*          V       = (float*)(ws + 6291456);            // 4 MB
    unsigned*       cand    = (unsigned*)(ws + 10485760);        // 16 MB
    // total ws use ~26 MB (well under proven 42.8 envelope)

    k_pre<<<N / ROWS_PRE, 256, 0, stream>>>(x, W1, b1, sq, sqs, Xh, U, V);
    k_pretau<<<N / 16, 256, 0, stream>>>(Xh, sq, sqs, tauf);
    k_main<<<dim3(NBX, 128), 256, 0, stream>>>(Xh, sq, tauf, cand, cntpart);
    k_exact<<<N / 4, 256, 0, stream>>>(x, sq, cntpart, cand, knn);
    k_aggout<<<N / 8, 256, 0, stream>>>(U, V, knn, W2, b2, out);
}